// Round 1
// baseline (684.169 us; speedup 1.0000x reference)
//
#include <hip/hip_runtime.h>
#include <cstdio>

// ---------------------------------------------------------------------------
// BiLSTM  B=64, T=512, D=256, H=256
// Plan:
//   P0: convert x, Wih_{f,b} to bf16; bias vectors; quantize Whh to int8 rows
//   P1: MFMA bf16 GEMM: xproj[d][b][t][n] = sum_k x[b,t,k]*Wih_d[n,k] + bias_d[n]
//   P2: recurrent kernel: 128 WGs (64 batch x 2 dir), 1024 thr, Whh int8 in
//       VGPRs (64 dwords/thread = 1 row), h int8-broadcast via LDS, dot4.
// ---------------------------------------------------------------------------

typedef unsigned short ushort_t;
typedef __attribute__((ext_vector_type(8))) short short8;
typedef __attribute__((ext_vector_type(4))) float f32x4;

__device__ __forceinline__ ushort_t f2bf(float f) {
    union { float f; unsigned u; } v; v.f = f;
    unsigned r = v.u + 0x7fffu + ((v.u >> 16) & 1u);
    return (ushort_t)(r >> 16);
}
__device__ __forceinline__ float bf2f(ushort_t h) {
    union { unsigned u; float f; } v; v.u = ((unsigned)h) << 16;
    return v.f;
}

__device__ __forceinline__ float fexp2(float x) {
#if __has_builtin(__builtin_amdgcn_exp2f)
    return __builtin_amdgcn_exp2f(x);
#else
    return exp2f(x);
#endif
}
__device__ __forceinline__ float frcp(float x) {
#if __has_builtin(__builtin_amdgcn_rcpf)
    return __builtin_amdgcn_rcpf(x);
#else
    return 1.0f / x;
#endif
}
__device__ __forceinline__ float fsig(float x) {
    // 1/(1+2^(-x*log2e)); robust at +-inf
    return frcp(1.0f + fexp2(-1.44269504089f * x));
}
__device__ __forceinline__ float ftanh(float x) {
    // (e^{2x}-1)/(e^{2x}+1) = 1 - 2/(e^{2x}+1); robust at +-inf
    float e = fexp2(2.88539008178f * x);
    return 1.0f - 2.0f * frcp(e + 1.0f);
}

__device__ __forceinline__ int dot4(int a, int b, int c) {
#if __has_builtin(__builtin_amdgcn_sdot4)
    return __builtin_amdgcn_sdot4(a, b, c, false);
#else
    int r = c;
    r += ((a << 24) >> 24) * ((b << 24) >> 24);
    r += ((a << 16) >> 24) * ((b << 16) >> 24);
    r += ((a << 8) >> 24) * ((b << 8) >> 24);
    r += (a >> 24) * (b >> 24);
    return r;
#endif
}

// ---------------------------------------------------------------------------
// P0a: fp32 -> bf16 (n multiple of 4)
__global__ __launch_bounds__(256) void k_f2bf(const float* __restrict__ in,
                                              ushort_t* __restrict__ out, int n) {
    int i = (blockIdx.x * 256 + threadIdx.x) * 4;
    if (i + 3 < n) {
        float4 v = *(const float4*)&in[i];
        ushort_t o0 = f2bf(v.x), o1 = f2bf(v.y), o2 = f2bf(v.z), o3 = f2bf(v.w);
        ushort4 o; o.x = o0; o.y = o1; o.z = o2; o.w = o3;
        *(ushort4*)&out[i] = o;
    }
}

// P0b: bias vectors biasv[d][n] = bih_d[n] + bhh_d[n]
__global__ __launch_bounds__(256) void k_bias(const float* __restrict__ bihf,
                                              const float* __restrict__ bhhf,
                                              const float* __restrict__ bihb,
                                              const float* __restrict__ bhhb,
                                              float* __restrict__ bv) {
    int i = blockIdx.x * 256 + threadIdx.x;
    if (i < 1024) bv[i] = bihf[i] + bhhf[i];
    else if (i < 2048) bv[i] = bihb[i - 1024] + bhhb[i - 1024];
}

// P0c: quantize Whh rows to int8, transposed layout wqT[d][kc][row] (kc = k/4)
// one wave per row; lane l handles k = 4l..4l+3
__global__ __launch_bounds__(256) void k_quant(const float* __restrict__ whhf,
                                               const float* __restrict__ whhb,
                                               int* __restrict__ wqT,
                                               float* __restrict__ fscale) {
    int rowg = blockIdx.x * 4 + (threadIdx.x >> 6);   // 0..2047
    int l = threadIdx.x & 63;
    int d = rowg >> 10;
    int row = rowg & 1023;
    const float* W = (d ? whhb : whhf) + (size_t)row * 256;
    float4 v = *(const float4*)&W[l * 4];
    float m = fmaxf(fmaxf(fabsf(v.x), fabsf(v.y)), fmaxf(fabsf(v.z), fabsf(v.w)));
    #pragma unroll
    for (int off = 32; off > 0; off >>= 1) m = fmaxf(m, __shfl_xor(m, off));
    float inv = (m > 0.0f) ? (127.0f / m) : 0.0f;
    int q0 = __float2int_rn(v.x * inv);
    int q1 = __float2int_rn(v.y * inv);
    int q2 = __float2int_rn(v.z * inv);
    int q3 = __float2int_rn(v.w * inv);
    q0 = min(127, max(-127, q0)); q1 = min(127, max(-127, q1));
    q2 = min(127, max(-127, q2)); q3 = min(127, max(-127, q3));
    int packed = (q0 & 255) | ((q1 & 255) << 8) | ((q2 & 255) << 16) | ((q3 & 255) << 24);
    wqT[d * 65536 + l * 1024 + row] = packed;
    if (l == 0) fscale[d * 1024 + row] = m / (127.0f * 127.0f);  // s_r/127
}

// ---------------------------------------------------------------------------
// P1: bf16 GEMM, C[m,n] = sum_k A[m,k]*B[n,k] + bias[n], store bf16
// A = xbf [32768 x 256], B = Wih_bf [1024 x 256] per dir.
// 128x128 tile, BK=32, 256 threads (4 waves as 2x2 of 64x64), mfma 16x16x32.
// XOR-swizzled LDS k-chunk columns to kill ds_read_b128 bank conflicts.
#define LDSOFF(r, kc) ((r) * 32 + ((((kc) + ((r) >> 1)) & 3) * 8))

__global__ __launch_bounds__(256) void k_gemm(const ushort_t* __restrict__ A,
                                              const ushort_t* __restrict__ Bw,
                                              const float* __restrict__ biasv,
                                              ushort_t* __restrict__ Xp) {
    const int dir = blockIdx.z;
    const ushort_t* Bmat = Bw + dir * 262144;
    const float* bv = biasv + dir * 1024;
    ushort_t* C = Xp + (size_t)dir * 33554432;
    const int tn = blockIdx.x;   // 0..7
    const int tm = blockIdx.y;   // 0..255
    const int tid = threadIdx.x;
    const int w = tid >> 6, l = tid & 63;
    const int wm = w & 1, wn = w >> 1;

    __shared__ ushort_t As[128 * 32];
    __shared__ ushort_t Bs[128 * 32];

    f32x4 acc[4][4];
    #pragma unroll
    for (int i = 0; i < 4; i++) {
        #pragma unroll
        for (int j = 0; j < 4; j++) { acc[i][j] = (f32x4){0.f, 0.f, 0.f, 0.f}; }
    }

    const int r0 = tid >> 2, c0 = tid & 3;            // chunk 0: rows 0..63
    const int r1 = (tid + 256) >> 2, c1 = tid & 3;    // chunk 1: rows 64..127

    for (int kb = 0; kb < 8; kb++) {
        __syncthreads();
        {
            short8 a0 = *(const short8*)&A[((size_t)(tm * 128 + r0)) * 256 + kb * 32 + c0 * 8];
            short8 a1 = *(const short8*)&A[((size_t)(tm * 128 + r1)) * 256 + kb * 32 + c1 * 8];
            short8 b0 = *(const short8*)&Bmat[((size_t)(tn * 128 + r0)) * 256 + kb * 32 + c0 * 8];
            short8 b1 = *(const short8*)&Bmat[((size_t)(tn * 128 + r1)) * 256 + kb * 32 + c1 * 8];
            *(short8*)&As[LDSOFF(r0, c0)] = a0;
            *(short8*)&As[LDSOFF(r1, c1)] = a1;
            *(short8*)&Bs[LDSOFF(r0, c0)] = b0;
            *(short8*)&Bs[LDSOFF(r1, c1)] = b1;
        }
        __syncthreads();
        short8 af[4], bf[4];
        const int q = l >> 4;
        #pragma unroll
        for (int mt = 0; mt < 4; mt++) {
            int rr = wm * 64 + mt * 16 + (l & 15);
            af[mt] = *(const short8*)&As[LDSOFF(rr, q)];
        }
        #pragma unroll
        for (int nt = 0; nt < 4; nt++) {
            int rr = wn * 64 + nt * 16 + (l & 15);
            bf[nt] = *(const short8*)&Bs[LDSOFF(rr, q)];
        }
        #pragma unroll
        for (int mt = 0; mt < 4; mt++) {
            #pragma unroll
            for (int nt = 0; nt < 4; nt++) {
                acc[mt][nt] = __builtin_amdgcn_mfma_f32_16x16x32_bf16(
                    af[mt], bf[nt], acc[mt][nt], 0, 0, 0);
            }
        }
    }
    // epilogue: C/D layout col = lane&15 (n), row = (lane>>4)*4 + reg (m)
    #pragma unroll
    for (int nt = 0; nt < 4; nt++) {
        int n = tn * 128 + wn * 64 + nt * 16 + (l & 15);
        float bn = bv[n];
        #pragma unroll
        for (int mt = 0; mt < 4; mt++) {
            #pragma unroll
            for (int r = 0; r < 4; r++) {
                int m = tm * 128 + wm * 64 + mt * 16 + (l >> 4) * 4 + r;
                C[(size_t)m * 1024 + n] = f2bf(acc[mt][nt][r] + bn);
            }
        }
    }
}

// ---------------------------------------------------------------------------
// P2: recurrence. grid (64 batch, 2 dir) x 1024 threads. Thread n owns Whh
// row n (int8, 64 dwords in VGPRs). Rows 0..255=i, 256..511=f, 512..767=g,
// 768..1023=o. Threads n<256 own c[n], h[n].
__device__ __forceinline__ int time_idx(int s, int len, int d) {
    int sc = (s < len - 1) ? s : (len - 1);
    return (d == 0) ? sc : (len - 1 - sc);
}

__global__ __launch_bounds__(1024) void k_rec(const ushort_t* __restrict__ xproj,
                                              const int* __restrict__ wqT,
                                              const float* __restrict__ fscale,
                                              const int* __restrict__ lens,
                                              float* __restrict__ out) {
    const int b = blockIdx.x, d = blockIdx.y;
    const int n = threadIdx.x;
    int len = lens[b];
    if (len < 1) len = 1;
    if (len > 512) len = 512;
    const ushort_t* xp = xproj + ((size_t)d * 64 + b) * 524288;  // 512*1024
    const int* wq = wqT + d * 65536;
    const float fr = fscale[d * 1024 + n];

    int w[64];
    #pragma unroll
    for (int kc = 0; kc < 64; kc++) w[kc] = wq[kc * 1024 + n];

    __shared__ int h8[64] __attribute__((aligned(16)));
    __shared__ float fA[256], gA[256], oA[256];

    if (n < 64) h8[n] = 0;

    // zero-fill this direction's half for t in [len, 512)
    {
        float4 z = {0.f, 0.f, 0.f, 0.f};
        int total4 = (512 - len) * 64;
        for (int i = n; i < total4; i += 1024) {
            int t = len + (i >> 6);
            int c4 = i & 63;
            *(float4*)&out[((size_t)b * 512 + t) * 512 + d * 256 + c4 * 4] = z;
        }
    }
    __syncthreads();

    const int gate = n >> 8, j = n & 255;
    float c_state = 0.0f;

    // prefetch pipeline (depth 2) on xproj
    float xv0 = bf2f(xp[(size_t)time_idx(0, len, d) * 1024 + n]);
    float xv1 = bf2f(xp[(size_t)time_idx(1, len, d) * 1024 + n]);

    for (int s = 0; s < len; s++) {
        float xv = xv0;
        xv0 = xv1;
        ushort_t xn = xp[(size_t)time_idx(s + 2, len, d) * 1024 + n];

        int acc = 0;
        #pragma unroll
        for (int kc = 0; kc < 16; kc++) {
            int4 hv = *(const int4*)&h8[kc * 4];   // wave-uniform -> LDS broadcast
            acc = dot4(w[kc * 4 + 0], hv.x, acc);
            acc = dot4(w[kc * 4 + 1], hv.y, acc);
            acc = dot4(w[kc * 4 + 2], hv.z, acc);
            acc = dot4(w[kc * 4 + 3], hv.w, acc);
        }
        float pre = xv + fr * (float)acc;

        float act;
        if (gate == 2) act = ftanh(pre);
        else act = fsig(pre);
        if (gate == 1) fA[j] = act;
        else if (gate == 2) gA[j] = act;
        else if (gate == 3) oA[j] = act;
        __syncthreads();

        if (gate == 0) {
            c_state = fA[j] * c_state + act * gA[j];
            float h = oA[j] * ftanh(c_state);
            int t = time_idx(s, len, d);
            out[((size_t)b * 512 + t) * 512 + d * 256 + j] = h;
            int q = __float2int_rn(h * 127.0f);
            q = min(127, max(-127, q));
            ((char*)h8)[j] = (char)q;
        }
        xv1 = bf2f(xn);
        __syncthreads();
    }
}

// ---------------------------------------------------------------------------
extern "C" void kernel_launch(void* const* d_in, const int* in_sizes, int n_in,
                              void* d_out, int out_size, void* d_ws, size_t ws_size,
                              hipStream_t stream) {
    (void)in_sizes; (void)n_in; (void)out_size;
    const float* x    = (const float*)d_in[0];
    const int*   lens = (const int*)d_in[1];
    const float* wihf = (const float*)d_in[2];
    const float* whhf = (const float*)d_in[3];
    const float* bihf = (const float*)d_in[4];
    const float* bhhf = (const float*)d_in[5];
    const float* wihb = (const float*)d_in[6];
    const float* whhb = (const float*)d_in[7];
    const float* bihb = (const float*)d_in[8];
    const float* bhhb = (const float*)d_in[9];
    float* out = (float*)d_out;

    const size_t REQ = 152584192;  // see offsets below
    if (ws_size < REQ) {
        fprintf(stderr, "kernel_launch: ws too small: %zu < %zu\n", ws_size, REQ);
    }
    char* ws = (char*)d_ws;
    ushort_t* xbf    = (ushort_t*)(ws + 0);          // 16,777,216 B
    ushort_t* wihbf  = (ushort_t*)(ws + 16777216);   //  1,048,576 B
    float*    biasv  = (float*)(ws + 17825792);      //      8,192 B
    int*      wqT    = (int*)(ws + 17833984);        //    524,288 B
    float*    fscale = (float*)(ws + 18358272);      //      8,192 B
    ushort_t* xproj  = (ushort_t*)(ws + 18366464);   // 134,217,728 B

    // P0
    k_f2bf<<<8192, 256, 0, stream>>>(x, xbf, 8388608);
    k_f2bf<<<256, 256, 0, stream>>>(wihf, wihbf, 262144);
    k_f2bf<<<256, 256, 0, stream>>>(wihb, wihbf + 262144, 262144);
    k_bias<<<8, 256, 0, stream>>>(bihf, bhhf, bihb, bhhb, biasv);
    k_quant<<<512, 256, 0, stream>>>(whhf, whhb, wqT, fscale);
    // P1
    k_gemm<<<dim3(8, 256, 2), 256, 0, stream>>>(xbf, wihbf, biasv, xproj);
    // P2
    k_rec<<<dim3(64, 2), 1024, 0, stream>>>(xproj, wqT, fscale, lens, out);
}